// Round 1
// baseline (13085.741 us; speedup 1.0000x reference)
//
#include <hip/hip_runtime.h>
#include <math.h>

#define N_NODES 100000
#define N_FEAT 500
#define N_HID 256
#define N_CLASS 40

// ---------------------------------------------------------------------------
// GEMM1: C[M,256] = A[M,500] @ W1[500,256] + b1   (f32, tiled 64x64x16, 4x4/thread)
// ---------------------------------------------------------------------------
#define G1_BM 64
#define G1_BN 64
#define G1_BK 16

__global__ __launch_bounds__(256) void gemm1_kernel(
    const float* __restrict__ A, const float* __restrict__ B,
    const float* __restrict__ bias, float* __restrict__ C, int M) {
  const int K = N_FEAT, N = N_HID;
  __shared__ float As[G1_BK][G1_BM];
  __shared__ float Bs[G1_BK][G1_BN];
  int tid = threadIdx.x;
  int tx = tid & 15, ty = tid >> 4;
  int bm = blockIdx.x * G1_BM;
  int bn = blockIdx.y * G1_BN;
  int lrow = tid >> 2;          // 0..63  (A loader row)
  int lc   = (tid & 3) << 2;    // 0,4,8,12 (A loader k-chunk)
  int brow = tid >> 4;          // 0..15  (B loader k)
  int bc   = (tid & 15) << 2;   // B loader col chunk

  float acc[4][4] = {};

  for (int k0 = 0; k0 < K; k0 += G1_BK) {
    // stage A (transposed into LDS)
    int arow = bm + lrow;
#pragma unroll
    for (int i = 0; i < 4; i++) {
      int k = k0 + lc + i;
      As[lc + i][lrow] = (arow < M && k < K) ? A[(size_t)arow * K + k] : 0.f;
    }
    // stage B
    {
      int k = k0 + brow;
      float4 v = make_float4(0.f, 0.f, 0.f, 0.f);
      if (k < K) v = *(const float4*)(B + (size_t)k * N + bn + bc);
      *(float4*)&Bs[brow][bc] = v;
    }
    __syncthreads();
#pragma unroll
    for (int kk = 0; kk < G1_BK; kk++) {
      float4 a = *(const float4*)&As[kk][ty << 2];
      float4 b = *(const float4*)&Bs[kk][tx << 2];
      float av[4] = {a.x, a.y, a.z, a.w};
      float bv[4] = {b.x, b.y, b.z, b.w};
#pragma unroll
      for (int i = 0; i < 4; i++)
#pragma unroll
        for (int j = 0; j < 4; j++) acc[i][j] = fmaf(av[i], bv[j], acc[i][j]);
    }
    __syncthreads();
  }

  float4 bv = *(const float4*)(bias + bn + (tx << 2));
#pragma unroll
  for (int i = 0; i < 4; i++) {
    int row = bm + (ty << 2) + i;
    if (row < M) {
      float4 v = make_float4(acc[i][0] + bv.x, acc[i][1] + bv.y,
                             acc[i][2] + bv.z, acc[i][3] + bv.w);
      *(float4*)(C + (size_t)row * N + bn + (tx << 2)) = v;
    }
  }
}

// ---------------------------------------------------------------------------
// SPMM (F=256): Y[row[e]] += val[e] * X[col[e]]   via atomics.
// One wave (64 lanes) per edge; each lane handles 4 consecutive features.
// ---------------------------------------------------------------------------
__global__ __launch_bounds__(256) void spmm_atomic_256(
    const int* __restrict__ er, const int* __restrict__ ec,
    const float* __restrict__ ev, const float* __restrict__ X,
    float* __restrict__ Y, int E) {
  unsigned idx = blockIdx.x * 256u + threadIdx.x;
  unsigned e = idx >> 6;
  if (e >= (unsigned)E) return;
  unsigned c = (idx & 63u) << 2;
  int row = er[e];
  int col = ec[e];
  float val = ev[e];
  float4 xv = *(const float4*)(X + (size_t)col * N_HID + c);
  float* dst = Y + (size_t)row * N_HID + c;
  atomicAdd(dst + 0, val * xv.x);
  atomicAdd(dst + 1, val * xv.y);
  atomicAdd(dst + 2, val * xv.z);
  atomicAdd(dst + 3, val * xv.w);
}

// ---------------------------------------------------------------------------
// SPMM (F=40): thread handles one (edge, 4-feature chunk); 10 chunks per edge.
// ---------------------------------------------------------------------------
__global__ __launch_bounds__(256) void spmm_atomic_40(
    const int* __restrict__ er, const int* __restrict__ ec,
    const float* __restrict__ ev, const float* __restrict__ X,
    float* __restrict__ Y, int E) {
  unsigned idx = blockIdx.x * 256u + threadIdx.x;
  unsigned e = __umulhi(idx, 0xCCCCCCCDu) >> 3;  // idx / 10
  if (e >= (unsigned)E) return;
  unsigned c = (idx - e * 10u) << 2;             // (idx % 10) * 4
  int row = er[e];
  int col = ec[e];
  float val = ev[e];
  float4 xv = *(const float4*)(X + (size_t)col * N_CLASS + c);
  float* dst = Y + (size_t)row * N_CLASS + c;
  atomicAdd(dst + 0, val * xv.x);
  atomicAdd(dst + 1, val * xv.y);
  atomicAdd(dst + 2, val * xv.z);
  atomicAdd(dst + 3, val * xv.w);
}

// ---------------------------------------------------------------------------
// GEMM2 (fused ReLU on input): O[M,40] = relu(H[M,256]) @ W2[256,40] + b2
// One thread per output row; W2 staged in LDS (40 KB).
// ---------------------------------------------------------------------------
__global__ __launch_bounds__(256) void gemm2_relu_kernel(
    const float* __restrict__ H, const float* __restrict__ W2,
    const float* __restrict__ b2, float* __restrict__ O, int M) {
  __shared__ float Ws[N_HID * N_CLASS];
  int tid = threadIdx.x;
  for (int i = tid; i < N_HID * N_CLASS; i += 256) Ws[i] = W2[i];
  __syncthreads();
  int m = blockIdx.x * 256 + tid;
  if (m >= M) return;
  float acc[N_CLASS];
#pragma unroll
  for (int n = 0; n < N_CLASS; n++) acc[n] = 0.f;
  const float* hrow = H + (size_t)m * N_HID;
  for (int k0 = 0; k0 < N_HID; k0 += 4) {
    float4 hv = *(const float4*)(hrow + k0);
    hv.x = fmaxf(hv.x, 0.f);
    hv.y = fmaxf(hv.y, 0.f);
    hv.z = fmaxf(hv.z, 0.f);
    hv.w = fmaxf(hv.w, 0.f);
#pragma unroll
    for (int n = 0; n < N_CLASS; n++) {
      acc[n] = fmaf(hv.x, Ws[(k0 + 0) * N_CLASS + n], acc[n]);
      acc[n] = fmaf(hv.y, Ws[(k0 + 1) * N_CLASS + n], acc[n]);
      acc[n] = fmaf(hv.z, Ws[(k0 + 2) * N_CLASS + n], acc[n]);
      acc[n] = fmaf(hv.w, Ws[(k0 + 3) * N_CLASS + n], acc[n]);
    }
  }
  float* orow = O + (size_t)m * N_CLASS;
#pragma unroll
  for (int n = 0; n < N_CLASS; n += 4) {
    float4 v = make_float4(acc[n] + b2[n], acc[n + 1] + b2[n + 1],
                           acc[n + 2] + b2[n + 2], acc[n + 3] + b2[n + 3]);
    *(float4*)(orow + n) = v;
  }
}

// ---------------------------------------------------------------------------
// log_softmax over 40 classes, one thread per row.
// ---------------------------------------------------------------------------
__global__ __launch_bounds__(256) void logsoftmax_40(
    const float* __restrict__ X, float* __restrict__ Out, int M) {
  int m = blockIdx.x * 256 + threadIdx.x;
  if (m >= M) return;
  const float* x = X + (size_t)m * N_CLASS;
  float v[N_CLASS];
  float mx = -INFINITY;
#pragma unroll
  for (int i = 0; i < N_CLASS; i += 4) {
    float4 t = *(const float4*)(x + i);
    v[i] = t.x; v[i + 1] = t.y; v[i + 2] = t.z; v[i + 3] = t.w;
    mx = fmaxf(mx, fmaxf(fmaxf(t.x, t.y), fmaxf(t.z, t.w)));
  }
  float s = 0.f;
#pragma unroll
  for (int i = 0; i < N_CLASS; i++) s += expf(v[i] - mx);
  float lse = mx + logf(s);
  float* orow = Out + (size_t)m * N_CLASS;
#pragma unroll
  for (int i = 0; i < N_CLASS; i += 4) {
    float4 t = make_float4(v[i] - lse, v[i + 1] - lse, v[i + 2] - lse, v[i + 3] - lse);
    *(float4*)(orow + i) = t;
  }
}

// ---------------------------------------------------------------------------
extern "C" void kernel_launch(void* const* d_in, const int* in_sizes, int n_in,
                              void* d_out, int out_size, void* d_ws, size_t ws_size,
                              hipStream_t stream) {
  const float* feat = (const float*)d_in[0];
  const int* er     = (const int*)d_in[1];
  const int* ec     = (const int*)d_in[2];
  const float* ev   = (const float*)d_in[3];
  const float* W1   = (const float*)d_in[4];
  const float* b1   = (const float*)d_in[5];
  const float* W2   = (const float*)d_in[6];
  const float* b2   = (const float*)d_in[7];
  float* out = (float*)d_out;
  const int M = N_NODES;
  const int E = in_sizes[1];

  char* ws = (char*)d_ws;
  const size_t H_BYTES = (size_t)N_NODES * N_HID * sizeof(float);  // 102,400,000
  float* h     = (float*)ws;                  // [M,256]
  float* hpost = (float*)(ws + H_BYTES);      // [M,256]
  float* o     = (float*)ws;                  // [M,40]  (reuses h region; h dead)
  float* o2    = (float*)(ws + 16000000);     // [M,40]

  // Layer 1: linear
  {
    dim3 grid((M + G1_BM - 1) / G1_BM, N_HID / G1_BN);
    gemm1_kernel<<<grid, 256, 0, stream>>>(feat, W1, b1, h, M);
  }
  // Layer 1: spmm (zero + atomic scatter)
  hipMemsetAsync(hpost, 0, H_BYTES, stream);
  {
    unsigned total = (unsigned)E * 64u;
    spmm_atomic_256<<<(total + 255) / 256, 256, 0, stream>>>(er, ec, ev, h, hpost, E);
  }
  // Layer 2: relu + linear
  gemm2_relu_kernel<<<(M + 255) / 256, 256, 0, stream>>>(hpost, W2, b2, o, M);
  // Layer 2: spmm
  hipMemsetAsync(o2, 0, (size_t)N_NODES * N_CLASS * sizeof(float), stream);
  {
    unsigned total = (unsigned)E * 10u;
    spmm_atomic_40<<<(total + 255) / 256, 256, 0, stream>>>(er, ec, ev, o, o2, E);
  }
  // log_softmax
  logsoftmax_40<<<(M + 255) / 256, 256, 0, stream>>>(o2, out, M);
}

// Round 2
// 1532.381 us; speedup vs baseline: 8.5395x; 8.5395x over previous
//
#include <hip/hip_runtime.h>
#include <hip/hip_bf16.h>
#include <math.h>

#define N_NODES 100000
#define N_FEAT 500
#define N_HID 256
#define N_CLASS 40

__device__ __forceinline__ float b2f(unsigned short u) {
  unsigned int x = ((unsigned int)u) << 16;
  union { unsigned int i; float f; } c; c.i = x; return c.f;
}

// ---------------------------------------------------------------------------
// GEMM1: H[M,256] = A[M,500] @ W1[500,256] + b1   (f32 compute, bf16 output)
// ---------------------------------------------------------------------------
#define G1_BM 64
#define G1_BN 64
#define G1_BK 16

__global__ __launch_bounds__(256) void gemm1_kernel(
    const float* __restrict__ A, const float* __restrict__ B,
    const float* __restrict__ bias, __hip_bfloat16* __restrict__ C, int M) {
  const int K = N_FEAT, N = N_HID;
  __shared__ float As[G1_BK][G1_BM];
  __shared__ float Bs[G1_BK][G1_BN];
  int tid = threadIdx.x;
  int tx = tid & 15, ty = tid >> 4;
  int bm = blockIdx.x * G1_BM;
  int bn = blockIdx.y * G1_BN;
  int lrow = tid >> 2;
  int lc   = (tid & 3) << 2;
  int brow = tid >> 4;
  int bc   = (tid & 15) << 2;

  float acc[4][4] = {};

  for (int k0 = 0; k0 < K; k0 += G1_BK) {
    int arow = bm + lrow;
#pragma unroll
    for (int i = 0; i < 4; i++) {
      int k = k0 + lc + i;
      As[lc + i][lrow] = (arow < M && k < K) ? A[(size_t)arow * K + k] : 0.f;
    }
    {
      int k = k0 + brow;
      float4 v = make_float4(0.f, 0.f, 0.f, 0.f);
      if (k < K) v = *(const float4*)(B + (size_t)k * N + bn + bc);
      *(float4*)&Bs[brow][bc] = v;
    }
    __syncthreads();
#pragma unroll
    for (int kk = 0; kk < G1_BK; kk++) {
      float4 a = *(const float4*)&As[kk][ty << 2];
      float4 b = *(const float4*)&Bs[kk][tx << 2];
      float av[4] = {a.x, a.y, a.z, a.w};
      float bv[4] = {b.x, b.y, b.z, b.w};
#pragma unroll
      for (int i = 0; i < 4; i++)
#pragma unroll
        for (int j = 0; j < 4; j++) acc[i][j] = fmaf(av[i], bv[j], acc[i][j]);
    }
    __syncthreads();
  }

  float4 bv = *(const float4*)(bias + bn + (tx << 2));
#pragma unroll
  for (int i = 0; i < 4; i++) {
    int row = bm + (ty << 2) + i;
    if (row < M) {
      __hip_bfloat16 p[4];
      p[0] = __float2bfloat16(acc[i][0] + bv.x);
      p[1] = __float2bfloat16(acc[i][1] + bv.y);
      p[2] = __float2bfloat16(acc[i][2] + bv.z);
      p[3] = __float2bfloat16(acc[i][3] + bv.w);
      *(ushort4*)(C + (size_t)row * N + bn + (tx << 2)) = *(ushort4*)p;
    }
  }
}

// ---------------------------------------------------------------------------
// CSR build: histogram -> exclusive scan -> scatter
// ---------------------------------------------------------------------------
__global__ __launch_bounds__(256) void hist_kernel(
    const int* __restrict__ er, int* __restrict__ cnt, int E) {
  int i = blockIdx.x * 256 + threadIdx.x;
  if (i < E) atomicAdd(&cnt[er[i]], 1);
}

// single-block exclusive scan of cnt[0..n-1] -> row_ptr[0..n]; cnt rewritten
// with the exclusive prefix (to serve as the scatter cursor).
__global__ __launch_bounds__(1024) void scan_kernel(
    int* __restrict__ cnt, int* __restrict__ row_ptr, int n) {
  __shared__ int wsum[16];
  __shared__ int s_carry;
  int tid = threadIdx.x, lane = tid & 63, wid = tid >> 6;
  if (tid == 0) s_carry = 0;
  __syncthreads();
  for (int base = 0; base < n; base += 1024) {
    int i = base + tid;
    int v = (i < n) ? cnt[i] : 0;
    int x = v;
#pragma unroll
    for (int off = 1; off < 64; off <<= 1) {
      int t = __shfl_up(x, off);
      if (lane >= off) x += t;
    }
    if (lane == 63) wsum[wid] = x;
    __syncthreads();  // S1
    if (tid < 16) {
      int w = wsum[tid];
#pragma unroll
      for (int off = 1; off < 16; off <<= 1) {
        int t = __shfl_up(w, off);
        if (tid >= off) w += t;
      }
      wsum[tid] = w;
    }
    __syncthreads();  // S2
    int carry = s_carry;
    int waveoff = wid ? wsum[wid - 1] : 0;
    int exc = carry + waveoff + (x - v);
    if (i < n) { row_ptr[i] = exc; cnt[i] = exc; }
    __syncthreads();  // S3
    if (tid == 0) s_carry = carry + wsum[15];
  }
  if (tid == 0) row_ptr[n] = s_carry;
}

__global__ __launch_bounds__(256) void scatter_kernel(
    const int* __restrict__ er, const int* __restrict__ ec,
    const float* __restrict__ ev, int* __restrict__ cursor,
    int* __restrict__ col_s, float* __restrict__ val_s, int E) {
  int i = blockIdx.x * 256 + threadIdx.x;
  if (i >= E) return;
  int r = er[i];
  int pos = atomicAdd(&cursor[r], 1);
  col_s[pos] = ec[i];
  val_s[pos] = ev[i];
}

// ---------------------------------------------------------------------------
// SPMM1 (CSR, F=256, bf16 X, fused ReLU): one wave per row, 4 feats/lane.
// ---------------------------------------------------------------------------
__global__ __launch_bounds__(256) void spmm_csr_256(
    const int* __restrict__ row_ptr, const int* __restrict__ col_s,
    const float* __restrict__ val_s, const __hip_bfloat16* __restrict__ X,
    float* __restrict__ Y, int M) {
  int wave = (blockIdx.x * 256 + threadIdx.x) >> 6;
  int lane = threadIdx.x & 63;
  if (wave >= M) return;
  int start = row_ptr[wave], end = row_ptr[wave + 1];
  float a0 = 0.f, a1 = 0.f, a2 = 0.f, a3 = 0.f;
  const __hip_bfloat16* Xl = X + (size_t)(lane << 2);
  for (int e = start; e < end; e++) {
    int col = col_s[e];
    float val = val_s[e];
    ushort4 xv = *(const ushort4*)(Xl + (size_t)col * N_HID);
    a0 = fmaf(val, b2f(xv.x), a0);
    a1 = fmaf(val, b2f(xv.y), a1);
    a2 = fmaf(val, b2f(xv.z), a2);
    a3 = fmaf(val, b2f(xv.w), a3);
  }
  float4 o = make_float4(fmaxf(a0, 0.f), fmaxf(a1, 0.f),
                         fmaxf(a2, 0.f), fmaxf(a3, 0.f));
  *(float4*)(Y + (size_t)wave * N_HID + (lane << 2)) = o;
}

// ---------------------------------------------------------------------------
// GEMM2: O[M,40] = Hpost[M,256] @ W2[256,40] + b2  (Hpost already ReLU'd)
// ---------------------------------------------------------------------------
__global__ __launch_bounds__(256) void gemm2_kernel(
    const float* __restrict__ H, const float* __restrict__ W2,
    const float* __restrict__ b2, float* __restrict__ O, int M) {
  __shared__ float Ws[N_HID * N_CLASS];
  int tid = threadIdx.x;
  for (int i = tid; i < N_HID * N_CLASS; i += 256) Ws[i] = W2[i];
  __syncthreads();
  int m = blockIdx.x * 256 + tid;
  if (m >= M) return;
  float acc[N_CLASS];
#pragma unroll
  for (int n = 0; n < N_CLASS; n++) acc[n] = 0.f;
  const float* hrow = H + (size_t)m * N_HID;
  for (int k0 = 0; k0 < N_HID; k0 += 4) {
    float4 hv = *(const float4*)(hrow + k0);
#pragma unroll
    for (int n = 0; n < N_CLASS; n++) {
      acc[n] = fmaf(hv.x, Ws[(k0 + 0) * N_CLASS + n], acc[n]);
      acc[n] = fmaf(hv.y, Ws[(k0 + 1) * N_CLASS + n], acc[n]);
      acc[n] = fmaf(hv.z, Ws[(k0 + 2) * N_CLASS + n], acc[n]);
      acc[n] = fmaf(hv.w, Ws[(k0 + 3) * N_CLASS + n], acc[n]);
    }
  }
  float* orow = O + (size_t)m * N_CLASS;
#pragma unroll
  for (int n = 0; n < N_CLASS; n += 4) {
    float4 v = make_float4(acc[n] + b2[n], acc[n + 1] + b2[n + 1],
                           acc[n + 2] + b2[n + 2], acc[n + 3] + b2[n + 3]);
    *(float4*)(orow + n) = v;
  }
}

// ---------------------------------------------------------------------------
// SPMM2 (CSR, F=40) + fused log_softmax: one wave per row, lanes 0..39 active.
// ---------------------------------------------------------------------------
__global__ __launch_bounds__(256) void spmm_csr_40_lsm(
    const int* __restrict__ row_ptr, const int* __restrict__ col_s,
    const float* __restrict__ val_s, const float* __restrict__ X,
    float* __restrict__ Out, int M) {
  int wave = (blockIdx.x * 256 + threadIdx.x) >> 6;
  int lane = threadIdx.x & 63;
  if (wave >= M) return;
  int start = row_ptr[wave], end = row_ptr[wave + 1];
  bool act = lane < N_CLASS;
  float acc = 0.f;
  for (int e = start; e < end; e++) {
    int col = col_s[e];
    float val = val_s[e];
    float xv = act ? X[(size_t)col * N_CLASS + lane] : 0.f;
    acc = fmaf(val, xv, acc);
  }
  float mv = act ? acc : -INFINITY;
#pragma unroll
  for (int off = 32; off; off >>= 1) mv = fmaxf(mv, __shfl_xor(mv, off));
  float ex = act ? expf(acc - mv) : 0.f;
  float s = ex;
#pragma unroll
  for (int off = 32; off; off >>= 1) s += __shfl_xor(s, off);
  float lse = mv + logf(s);
  if (act) Out[(size_t)wave * N_CLASS + lane] = acc - lse;
}

// ---------------------------------------------------------------------------
extern "C" void kernel_launch(void* const* d_in, const int* in_sizes, int n_in,
                              void* d_out, int out_size, void* d_ws, size_t ws_size,
                              hipStream_t stream) {
  const float* feat = (const float*)d_in[0];
  const int* er     = (const int*)d_in[1];
  const int* ec     = (const int*)d_in[2];
  const float* ev   = (const float*)d_in[3];
  const float* W1   = (const float*)d_in[4];
  const float* b1   = (const float*)d_in[5];
  const float* W2   = (const float*)d_in[6];
  const float* b2   = (const float*)d_in[7];
  float* out = (float*)d_out;
  const int M = N_NODES;
  const int E = in_sizes[1];

  char* ws = (char*)d_ws;
  // layout (bytes):
  //   h (bf16)   [0,            51,200,000)
  //   hpost(f32) [51,200,000,  153,600,000)
  //   row_ptr    [153,600,000, +400,004)
  //   cursor     [154,000,016, +400,000)
  //   col_s      [154,400,032, +12,800,000)
  //   val_s      [167,200,032, +12,800,000)   end = 180,000,032
  //   o (f32)    [0, 16,000,000)              (reuses h after spmm1)
  __hip_bfloat16* h = (__hip_bfloat16*)ws;
  float* hpost = (float*)(ws + 51200000);
  int* row_ptr = (int*)(ws + 153600000);
  int* cursor  = (int*)(ws + 154000016);
  int* col_s   = (int*)(ws + 154400032);
  float* val_s = (float*)(ws + 167200032);
  float* o     = (float*)ws;

  // --- CSR build ---
  hipMemsetAsync(cursor, 0, (size_t)M * sizeof(int), stream);
  hist_kernel<<<(E + 255) / 256, 256, 0, stream>>>(er, cursor, E);
  scan_kernel<<<1, 1024, 0, stream>>>(cursor, row_ptr, M);
  scatter_kernel<<<(E + 255) / 256, 256, 0, stream>>>(er, ec, ev, cursor,
                                                      col_s, val_s, E);
  // --- layer 1 ---
  {
    dim3 grid((M + G1_BM - 1) / G1_BM, N_HID / G1_BN);
    gemm1_kernel<<<grid, 256, 0, stream>>>(feat, W1, b1, h, M);
  }
  spmm_csr_256<<<(M + 3) / 4, 256, 0, stream>>>(row_ptr, col_s, val_s, h,
                                                hpost, M);
  // --- layer 2 ---
  gemm2_kernel<<<(M + 255) / 256, 256, 0, stream>>>(hpost, W2, b2, o, M);
  spmm_csr_40_lsm<<<(M + 3) / 4, 256, 0, stream>>>(row_ptr, col_s, val_s, o,
                                                   out, M);
}

// Round 3
// 928.600 us; speedup vs baseline: 14.0919x; 1.6502x over previous
//
#include <hip/hip_runtime.h>
#include <hip/hip_bf16.h>
#include <math.h>

#define N_NODES 100000
#define N_FEAT 500
#define N_HID 256
#define N_CLASS 40

typedef float f32x4 __attribute__((ext_vector_type(4)));
typedef short short8 __attribute__((ext_vector_type(8)));
typedef unsigned short u16x8 __attribute__((ext_vector_type(8)));

__device__ __forceinline__ float b2f(unsigned short u) {
  union { unsigned int i; float f; } c; c.i = ((unsigned int)u) << 16; return c.f;
}
__device__ __forceinline__ unsigned short f2bu(float x) {
  __hip_bfloat16 b = __float2bfloat16(x);
  union { __hip_bfloat16 b; unsigned short u; } c; c.b = b; return c.u;
}
__device__ __forceinline__ void gload_lds16(const void* gptr, void* lptr) {
  __builtin_amdgcn_global_load_lds(
      (const __attribute__((address_space(1))) unsigned int*)gptr,
      (__attribute__((address_space(3))) unsigned int*)lptr, 16, 0, 0);
}

// ---------------------------------------------------------------------------
// cast W1[500][256] f32 -> W1T_sw[256][512] bf16, transposed, zero-padded,
// chunk-swizzled: W1T_sw[col][g*64 + c*8 + j] = W1T[col][g*64 + (c^(col&7))*8 + j]
// so that linear global_load_lds staging + XOR-swizzled ds_read is correct.
// ---------------------------------------------------------------------------
__global__ __launch_bounds__(256) void cast_w1(
    const float* __restrict__ W1, unsigned short* __restrict__ Bsw) {
  int t = blockIdx.x * 256 + threadIdx.x;     // 0..16383 = 256 cols x 64 chunks
  int col = t >> 6, ch = t & 63;
  int g = ch >> 3, c = ch & 7;
  int c_src = c ^ (col & 7);
  int k = g * 64 + c_src * 8;
  u16x8 o;
#pragma unroll
  for (int j = 0; j < 8; j++) {
    int kk = k + j;
    o[j] = (kk < N_FEAT) ? f2bu(W1[(size_t)kk * N_HID + col]) : (unsigned short)0;
  }
  *(u16x8*)(Bsw + (size_t)col * 512 + g * 64 + c * 8) = o;
}

// ---------------------------------------------------------------------------
// GEMM1 (bf16 MFMA): H[M,256] = A[M,500] @ W1 + b1, bf16 out.
// BM=128, BN=256 (full N -> A read once), BK=64, 512 threads = 8 waves (2x4).
// A: f32 global -> cvt bf16 -> swizzled ds_write. B: pre-swizzled global ->
// linear global_load_lds. Reads: XOR chunk swizzle (T2).
// ---------------------------------------------------------------------------
__global__ __launch_bounds__(512) void gemm1_mfma(
    const float* __restrict__ A, const unsigned short* __restrict__ Bsw,
    const float* __restrict__ b1, unsigned short* __restrict__ H, int M) {
  __shared__ __align__(16) char smem[49152];
  char* sA = smem;            // [128 rows][128 B]  (64 bf16 per row)
  char* sB = smem + 16384;    // [256 cols][128 B]
  int tid = threadIdx.x;
  int lane = tid & 63, w = tid >> 6;
  int wr = w >> 2, wc = w & 3;
  int bm = blockIdx.x * 128;

  f32x4 acc[4][4];
#pragma unroll
  for (int m = 0; m < 4; m++)
#pragma unroll
    for (int n = 0; n < 4; n++) acc[m][n] = (f32x4)0.f;

  for (int s = 0; s < 8; s++) {
    int k0 = s * 64;
    // stage A: 2048 float4 loads / 512 thr = 4 each; cvt; swizzled ds_write
#pragma unroll
    for (int i = 0; i < 4; i++) {
      int f4 = i * 512 + tid;
      int row = f4 >> 4, cidx = f4 & 15;
      int grow = bm + row;
      int k = k0 + cidx * 4;
      float4 v = make_float4(0.f, 0.f, 0.f, 0.f);
      if (grow < M && k < N_FEAT) v = *(const float4*)(A + (size_t)grow * N_FEAT + k);
      ushort4 u;
      u.x = f2bu(v.x); u.y = f2bu(v.y); u.z = f2bu(v.z); u.w = f2bu(v.w);
      int chunk = cidx >> 1, sub = cidx & 1;
      int byte = row * 128 + (((chunk ^ (row & 7))) << 4) + (sub << 3);
      *(ushort4*)(sA + byte) = u;
    }
    // stage B: 32KB / (512 thr * 16B) = 4 global_load_lds each (linear dest)
#pragma unroll
    for (int j = 0; j < 4; j++) {
      int base = j * 8192 + w * 1024;           // wave-uniform LDS dest
      int L = base + lane * 16;                 // this lane's dest
      int col = L >> 7, c = (L >> 4) & 7;
      const char* g = (const char*)Bsw + (size_t)col * 1024 + s * 128 + c * 16;
      gload_lds16(g, sB + base);
    }
    __syncthreads();
    // compute: 2 x (8 ds_read_b128 + 16 MFMA)
#pragma unroll
    for (int kk = 0; kk < 2; kk++) {
      int cw = kk * 4 + (lane >> 4);
      short8 af[4], bg[4];
#pragma unroll
      for (int m = 0; m < 4; m++) {
        int ar = wr * 64 + m * 16 + (lane & 15);
        af[m] = *(const short8*)(sA + ar * 128 + ((cw ^ (ar & 7)) << 4));
      }
#pragma unroll
      for (int n = 0; n < 4; n++) {
        int bc = wc * 64 + n * 16 + (lane & 15);
        bg[n] = *(const short8*)(sB + bc * 128 + ((cw ^ (bc & 7)) << 4));
      }
#pragma unroll
      for (int m = 0; m < 4; m++)
#pragma unroll
        for (int n = 0; n < 4; n++)
          acc[m][n] = __builtin_amdgcn_mfma_f32_16x16x32_bf16(af[m], bg[n], acc[m][n], 0, 0, 0);
    }
    __syncthreads();
  }

  // epilogue: C/D layout col=lane&15, row=(lane>>4)*4+reg  [m89]
  float bias[4];
#pragma unroll
  for (int n = 0; n < 4; n++) bias[n] = b1[wc * 64 + n * 16 + (lane & 15)];
#pragma unroll
  for (int m = 0; m < 4; m++) {
#pragma unroll
    for (int r = 0; r < 4; r++) {
      int row = bm + wr * 64 + m * 16 + ((lane >> 4) << 2) + r;
      if (row < M) {
#pragma unroll
        for (int n = 0; n < 4; n++) {
          int col = wc * 64 + n * 16 + (lane & 15);
          H[(size_t)row * N_HID + col] = f2bu(acc[m][n][r] + bias[n]);
        }
      }
    }
  }
}

// ---------------------------------------------------------------------------
// CSR build: hist -> 3-phase parallel scan -> scatter
// ---------------------------------------------------------------------------
__global__ __launch_bounds__(256) void hist_kernel(
    const int* __restrict__ er, int* __restrict__ cnt, int E) {
  int i = blockIdx.x * 256 + threadIdx.x;
  if (i < E) atomicAdd(&cnt[er[i]], 1);
}

// per-1024-block scan: cnt[i] -> exclusive-within-block; bsum[b] = block total
__global__ __launch_bounds__(1024) void scan1_kernel(
    int* __restrict__ cnt, int* __restrict__ bsum, int n) {
  __shared__ int wsum[16];
  int tid = threadIdx.x, lane = tid & 63, wid = tid >> 6;
  int i = blockIdx.x * 1024 + tid;
  int v = (i < n) ? cnt[i] : 0;
  int x = v;
#pragma unroll
  for (int off = 1; off < 64; off <<= 1) {
    int t = __shfl_up(x, off);
    if (lane >= off) x += t;
  }
  if (lane == 63) wsum[wid] = x;
  __syncthreads();
  if (tid < 16) {
    int ws = wsum[tid];
#pragma unroll
    for (int off = 1; off < 16; off <<= 1) {
      int t = __shfl_up(ws, off);
      if (tid >= off) ws += t;
    }
    wsum[tid] = ws;
  }
  __syncthreads();
  int excl = (wid ? wsum[wid - 1] : 0) + x - v;
  if (i < n) cnt[i] = excl;
  if (tid == 0) bsum[blockIdx.x] = wsum[15];
}

// single-wave scan of nb block sums -> exclusive; writes grand total to row_ptr[n]
__global__ __launch_bounds__(64) void scan2_kernel(
    int* __restrict__ bsum, int* __restrict__ row_ptr, int nb, int n) {
  int lane = threadIdx.x;
  int carry = 0;
  for (int base = 0; base < nb; base += 64) {
    int i = base + lane;
    int v = (i < nb) ? bsum[i] : 0;
    int x = v;
#pragma unroll
    for (int off = 1; off < 64; off <<= 1) {
      int t = __shfl_up(x, off);
      if (lane >= off) x += t;
    }
    if (i < nb) bsum[i] = carry + x - v;
    carry += __shfl(x, 63);
  }
  if (lane == 0) row_ptr[n] = carry;
}

__global__ __launch_bounds__(256) void scan3_kernel(
    int* __restrict__ cnt, const int* __restrict__ bsum,
    int* __restrict__ row_ptr, int n) {
  int i = blockIdx.x * 256 + threadIdx.x;
  if (i >= n) return;
  int v = cnt[i] + bsum[i >> 10];
  cnt[i] = v;        // scatter cursor
  row_ptr[i] = v;
}

__global__ __launch_bounds__(256) void scatter_kernel(
    const int* __restrict__ er, const int* __restrict__ ec,
    const float* __restrict__ ev, int* __restrict__ cursor,
    int* __restrict__ col_s, float* __restrict__ val_s, int E) {
  int i = blockIdx.x * 256 + threadIdx.x;
  if (i >= E) return;
  int r = er[i];
  int pos = atomicAdd(&cursor[r], 1);
  col_s[pos] = ec[i];
  val_s[pos] = ev[i];
}

// ---------------------------------------------------------------------------
// SPMM1 (CSR, F=256, bf16 in/out, fused ReLU): wave/row, 4 feats/lane, unroll 2
// ---------------------------------------------------------------------------
__global__ __launch_bounds__(256) void spmm_csr_256(
    const int* __restrict__ row_ptr, const int* __restrict__ col_s,
    const float* __restrict__ val_s, const unsigned short* __restrict__ X,
    unsigned short* __restrict__ Y, int M) {
  int wave = (blockIdx.x * 256 + threadIdx.x) >> 6;
  int lane = threadIdx.x & 63;
  if (wave >= M) return;
  int start = row_ptr[wave], end = row_ptr[wave + 1];
  float a0 = 0.f, a1 = 0.f, a2 = 0.f, a3 = 0.f;
  const unsigned short* Xl = X + (lane << 2);
  int e = start;
  for (; e + 2 <= end; e += 2) {
    int c0 = col_s[e], c1 = col_s[e + 1];
    float v0 = val_s[e], v1 = val_s[e + 1];
    ushort4 x0 = *(const ushort4*)(Xl + (size_t)c0 * N_HID);
    ushort4 x1 = *(const ushort4*)(Xl + (size_t)c1 * N_HID);
    a0 = fmaf(v0, b2f(x0.x), a0); a1 = fmaf(v0, b2f(x0.y), a1);
    a2 = fmaf(v0, b2f(x0.z), a2); a3 = fmaf(v0, b2f(x0.w), a3);
    a0 = fmaf(v1, b2f(x1.x), a0); a1 = fmaf(v1, b2f(x1.y), a1);
    a2 = fmaf(v1, b2f(x1.z), a2); a3 = fmaf(v1, b2f(x1.w), a3);
  }
  if (e < end) {
    int c0 = col_s[e];
    float v0 = val_s[e];
    ushort4 x0 = *(const ushort4*)(Xl + (size_t)c0 * N_HID);
    a0 = fmaf(v0, b2f(x0.x), a0); a1 = fmaf(v0, b2f(x0.y), a1);
    a2 = fmaf(v0, b2f(x0.z), a2); a3 = fmaf(v0, b2f(x0.w), a3);
  }
  ushort4 o;
  o.x = f2bu(fmaxf(a0, 0.f)); o.y = f2bu(fmaxf(a1, 0.f));
  o.z = f2bu(fmaxf(a2, 0.f)); o.w = f2bu(fmaxf(a3, 0.f));
  *(ushort4*)(Y + (size_t)wave * N_HID + (lane << 2)) = o;
}

// ---------------------------------------------------------------------------
// GEMM2: O[M,40] = Hpost[M,256](bf16) @ W2[256,40] + b2; 2 rows/thread.
// Ws LDS reads are wave-broadcast (same addr) -> conflict-free.
// ---------------------------------------------------------------------------
__global__ __launch_bounds__(256) void gemm2_kernel(
    const unsigned short* __restrict__ H, const float* __restrict__ W2,
    const float* __restrict__ b2, float* __restrict__ O, int M) {
  __shared__ float Ws[N_HID * N_CLASS];
  __shared__ float sb2[N_CLASS];
  int tid = threadIdx.x;
  for (int i = tid; i < N_HID * N_CLASS; i += 256) Ws[i] = W2[i];
  if (tid < N_CLASS) sb2[tid] = b2[tid];
  __syncthreads();
  int r0 = (blockIdx.x * 256 + tid) * 2;
  if (r0 >= M) return;
  int r1 = r0 + 1;
  bool has1 = r1 < M;
  float acc0[N_CLASS], acc1[N_CLASS];
#pragma unroll
  for (int n = 0; n < N_CLASS; n++) { acc0[n] = sb2[n]; acc1[n] = sb2[n]; }
  const unsigned short* h0 = H + (size_t)r0 * N_HID;
  const unsigned short* h1 = H + (size_t)(has1 ? r1 : r0) * N_HID;
  for (int k0 = 0; k0 < N_HID; k0 += 8) {
    u16x8 va = *(const u16x8*)(h0 + k0);
    u16x8 vb = *(const u16x8*)(h1 + k0);
#pragma unroll
    for (int j = 0; j < 8; j++) {
      float a0 = b2f(va[j]), a1 = b2f(vb[j]);
      const float* wrow = &Ws[(k0 + j) * N_CLASS];
#pragma unroll
      for (int n = 0; n < N_CLASS; n++) {
        float wv = wrow[n];
        acc0[n] = fmaf(a0, wv, acc0[n]);
        acc1[n] = fmaf(a1, wv, acc1[n]);
      }
    }
  }
  float* o0 = O + (size_t)r0 * N_CLASS;
#pragma unroll
  for (int n = 0; n < N_CLASS; n += 4) {
    *(float4*)(o0 + n) = make_float4(acc0[n], acc0[n + 1], acc0[n + 2], acc0[n + 3]);
  }
  if (has1) {
    float* o1 = O + (size_t)r1 * N_CLASS;
#pragma unroll
    for (int n = 0; n < N_CLASS; n += 4) {
      *(float4*)(o1 + n) = make_float4(acc1[n], acc1[n + 1], acc1[n + 2], acc1[n + 3]);
    }
  }
}

// ---------------------------------------------------------------------------
// SPMM2 (CSR, F=40) + fused log_softmax: wave/row, lanes 0..39, unroll 2
// ---------------------------------------------------------------------------
__global__ __launch_bounds__(256) void spmm_csr_40_lsm(
    const int* __restrict__ row_ptr, const int* __restrict__ col_s,
    const float* __restrict__ val_s, const float* __restrict__ X,
    float* __restrict__ Out, int M) {
  int wave = (blockIdx.x * 256 + threadIdx.x) >> 6;
  int lane = threadIdx.x & 63;
  if (wave >= M) return;
  int start = row_ptr[wave], end = row_ptr[wave + 1];
  bool act = lane < N_CLASS;
  int ln = act ? lane : 0;
  float acc = 0.f;
  int e = start;
  for (; e + 2 <= end; e += 2) {
    int c0 = col_s[e], c1 = col_s[e + 1];
    float v0 = val_s[e], v1 = val_s[e + 1];
    float x0 = X[(size_t)c0 * N_CLASS + ln];
    float x1 = X[(size_t)c1 * N_CLASS + ln];
    acc = fmaf(v0, x0, acc);
    acc = fmaf(v1, x1, acc);
  }
  if (e < end) {
    acc = fmaf(val_s[e], X[(size_t)col_s[e] * N_CLASS + ln], acc);
  }
  float mv = act ? acc : -INFINITY;
#pragma unroll
  for (int off = 32; off; off >>= 1) mv = fmaxf(mv, __shfl_xor(mv, off));
  float ex = act ? expf(acc - mv) : 0.f;
  float s = ex;
#pragma unroll
  for (int off = 32; off; off >>= 1) s += __shfl_xor(s, off);
  float lse = mv + logf(s);
  if (act) Out[(size_t)wave * N_CLASS + lane] = acc - lse;
}

// ---------------------------------------------------------------------------
extern "C" void kernel_launch(void* const* d_in, const int* in_sizes, int n_in,
                              void* d_out, int out_size, void* d_ws, size_t ws_size,
                              hipStream_t stream) {
  const float* feat = (const float*)d_in[0];
  const int* er     = (const int*)d_in[1];
  const int* ec     = (const int*)d_in[2];
  const float* ev   = (const float*)d_in[3];
  const float* W1   = (const float*)d_in[4];
  const float* b1   = (const float*)d_in[5];
  const float* W2   = (const float*)d_in[6];
  const float* b2   = (const float*)d_in[7];
  float* out = (float*)d_out;
  const int M = N_NODES;
  const int E = in_sizes[1];

  char* ws = (char*)d_ws;
  unsigned short* h     = (unsigned short*)(ws);                 // 51.2 MB bf16
  unsigned short* hpost = (unsigned short*)(ws + 51200000);      // 51.2 MB bf16
  float* o              = (float*)(ws + 102400000);              // 16 MB f32
  int* row_ptr          = (int*)(ws + 118400000);                // 400,004 B
  int* cursor           = (int*)(ws + 118800016);                // 400,000 B
  int* bsum             = (int*)(ws + 119200032);                // 512 B
  int* col_s            = (int*)(ws + 119200576);                // 12.8 MB
  float* val_s          = (float*)(ws + 132000576);              // 12.8 MB
  unsigned short* W1Tsw = (unsigned short*)(ws + 144800576);     // 256 KB

  const int NB1 = (M + 1023) / 1024;  // 98

  // weights precast (tiny)
  cast_w1<<<64, 256, 0, stream>>>(W1, W1Tsw);
  // CSR build
  hipMemsetAsync(cursor, 0, (size_t)M * sizeof(int), stream);
  hist_kernel<<<(E + 255) / 256, 256, 0, stream>>>(er, cursor, E);
  scan1_kernel<<<NB1, 1024, 0, stream>>>(cursor, bsum, M);
  scan2_kernel<<<1, 64, 0, stream>>>(bsum, row_ptr, NB1, M);
  scan3_kernel<<<(M + 255) / 256, 256, 0, stream>>>(cursor, bsum, row_ptr, M);
  scatter_kernel<<<(E + 255) / 256, 256, 0, stream>>>(er, ec, ev, cursor,
                                                      col_s, val_s, E);
  // layer 1
  gemm1_mfma<<<(M + 127) / 128, 512, 0, stream>>>(feat, W1Tsw, b1, h, M);
  spmm_csr_256<<<(M + 3) / 4, 256, 0, stream>>>(row_ptr, col_s, val_s, h, hpost, M);
  // layer 2
  gemm2_kernel<<<(M + 511) / 512, 256, 0, stream>>>(hpost, W2, b2, o, M);
  spmm_csr_40_lsm<<<(M + 3) / 4, 256, 0, stream>>>(row_ptr, col_s, val_s, o, out, M);
}

// Round 4
// 795.716 us; speedup vs baseline: 16.4452x; 1.1670x over previous
//
#include <hip/hip_runtime.h>
#include <hip/hip_bf16.h>
#include <math.h>

#define N_NODES 100000
#define N_FEAT 500
#define N_HID 256
#define N_CLASS 40

typedef float f32x4 __attribute__((ext_vector_type(4)));
typedef short short8 __attribute__((ext_vector_type(8)));
typedef unsigned short u16x8 __attribute__((ext_vector_type(8)));

__device__ __forceinline__ float b2f(unsigned short u) {
  union { unsigned int i; float f; } c; c.i = ((unsigned int)u) << 16; return c.f;
}
__device__ __forceinline__ unsigned short f2bu(float x) {
  __hip_bfloat16 b = __float2bfloat16(x);
  union { __hip_bfloat16 b; unsigned short u; } c; c.b = b; return c.u;
}
__device__ __forceinline__ void gload_lds16(const void* gptr, void* lptr) {
  __builtin_amdgcn_global_load_lds(
      (const __attribute__((address_space(1))) unsigned int*)gptr,
      (__attribute__((address_space(3))) unsigned int*)lptr, 16, 0, 0);
}

// ---------------------------------------------------------------------------
// cast W1[500][256] f32 -> W1T_sw[256][512] bf16 (transposed, padded, swizzled)
// ---------------------------------------------------------------------------
__global__ __launch_bounds__(256) void cast_w1(
    const float* __restrict__ W1, unsigned short* __restrict__ Bsw) {
  int t = blockIdx.x * 256 + threadIdx.x;
  int col = t >> 6, ch = t & 63;
  int g = ch >> 3, c = ch & 7;
  int c_src = c ^ (col & 7);
  int k = g * 64 + c_src * 8;
  u16x8 o;
#pragma unroll
  for (int j = 0; j < 8; j++) {
    int kk = k + j;
    o[j] = (kk < N_FEAT) ? f2bu(W1[(size_t)kk * N_HID + col]) : (unsigned short)0;
  }
  *(u16x8*)(Bsw + (size_t)col * 512 + g * 64 + c * 8) = o;
}

// ---------------------------------------------------------------------------
// GEMM1 (bf16 MFMA): H[M,256] = A[M,500] @ W1 + b1, bf16 out. (unchanged)
// ---------------------------------------------------------------------------
__global__ __launch_bounds__(512) void gemm1_mfma(
    const float* __restrict__ A, const unsigned short* __restrict__ Bsw,
    const float* __restrict__ b1, unsigned short* __restrict__ H, int M) {
  __shared__ __align__(16) char smem[49152];
  char* sA = smem;
  char* sB = smem + 16384;
  int tid = threadIdx.x;
  int lane = tid & 63, w = tid >> 6;
  int wr = w >> 2, wc = w & 3;
  int bm = blockIdx.x * 128;

  f32x4 acc[4][4];
#pragma unroll
  for (int m = 0; m < 4; m++)
#pragma unroll
    for (int n = 0; n < 4; n++) acc[m][n] = (f32x4)0.f;

  for (int s = 0; s < 8; s++) {
    int k0 = s * 64;
#pragma unroll
    for (int i = 0; i < 4; i++) {
      int f4 = i * 512 + tid;
      int row = f4 >> 4, cidx = f4 & 15;
      int grow = bm + row;
      int k = k0 + cidx * 4;
      float4 v = make_float4(0.f, 0.f, 0.f, 0.f);
      if (grow < M && k < N_FEAT) v = *(const float4*)(A + (size_t)grow * N_FEAT + k);
      ushort4 u;
      u.x = f2bu(v.x); u.y = f2bu(v.y); u.z = f2bu(v.z); u.w = f2bu(v.w);
      int chunk = cidx >> 1, sub = cidx & 1;
      int byte = row * 128 + (((chunk ^ (row & 7))) << 4) + (sub << 3);
      *(ushort4*)(sA + byte) = u;
    }
#pragma unroll
    for (int j = 0; j < 4; j++) {
      int base = j * 8192 + w * 1024;
      int L = base + lane * 16;
      int col = L >> 7, c = (L >> 4) & 7;
      const char* g = (const char*)Bsw + (size_t)col * 1024 + s * 128 + c * 16;
      gload_lds16(g, sB + base);
    }
    __syncthreads();
#pragma unroll
    for (int kk = 0; kk < 2; kk++) {
      int cw = kk * 4 + (lane >> 4);
      short8 af[4], bg[4];
#pragma unroll
      for (int m = 0; m < 4; m++) {
        int ar = wr * 64 + m * 16 + (lane & 15);
        af[m] = *(const short8*)(sA + ar * 128 + ((cw ^ (ar & 7)) << 4));
      }
#pragma unroll
      for (int n = 0; n < 4; n++) {
        int bc = wc * 64 + n * 16 + (lane & 15);
        bg[n] = *(const short8*)(sB + bc * 128 + ((cw ^ (bc & 7)) << 4));
      }
#pragma unroll
      for (int m = 0; m < 4; m++)
#pragma unroll
        for (int n = 0; n < 4; n++)
          acc[m][n] = __builtin_amdgcn_mfma_f32_16x16x32_bf16(af[m], bg[n], acc[m][n], 0, 0, 0);
    }
    __syncthreads();
  }

  float bias[4];
#pragma unroll
  for (int n = 0; n < 4; n++) bias[n] = b1[wc * 64 + n * 16 + (lane & 15)];
#pragma unroll
  for (int m = 0; m < 4; m++) {
#pragma unroll
    for (int r = 0; r < 4; r++) {
      int row = bm + wr * 64 + m * 16 + ((lane >> 4) << 2) + r;
      if (row < M) {
#pragma unroll
        for (int n = 0; n < 4; n++) {
          int col = wc * 64 + n * 16 + (lane & 15);
          H[(size_t)row * N_HID + col] = f2bu(acc[m][n][r] + bias[n]);
        }
      }
    }
  }
}

// ---------------------------------------------------------------------------
// CSR build: hist -> 3-phase scan -> scatter (packed int2 {col, val_bits})
// ---------------------------------------------------------------------------
__global__ __launch_bounds__(256) void hist_kernel(
    const int* __restrict__ er, int* __restrict__ cnt, int E) {
  int i = blockIdx.x * 256 + threadIdx.x;
  if (i < E) atomicAdd(&cnt[er[i]], 1);
}

__global__ __launch_bounds__(1024) void scan1_kernel(
    int* __restrict__ cnt, int* __restrict__ bsum, int n) {
  __shared__ int wsum[16];
  int tid = threadIdx.x, lane = tid & 63, wid = tid >> 6;
  int i = blockIdx.x * 1024 + tid;
  int v = (i < n) ? cnt[i] : 0;
  int x = v;
#pragma unroll
  for (int off = 1; off < 64; off <<= 1) {
    int t = __shfl_up(x, off);
    if (lane >= off) x += t;
  }
  if (lane == 63) wsum[wid] = x;
  __syncthreads();
  if (tid < 16) {
    int ws = wsum[tid];
#pragma unroll
    for (int off = 1; off < 16; off <<= 1) {
      int t = __shfl_up(ws, off);
      if (tid >= off) ws += t;
    }
    wsum[tid] = ws;
  }
  __syncthreads();
  int excl = (wid ? wsum[wid - 1] : 0) + x - v;
  if (i < n) cnt[i] = excl;
  if (tid == 0) bsum[blockIdx.x] = wsum[15];
}

__global__ __launch_bounds__(64) void scan2_kernel(
    int* __restrict__ bsum, int* __restrict__ row_ptr, int nb, int n) {
  int lane = threadIdx.x;
  int carry = 0;
  for (int base = 0; base < nb; base += 64) {
    int i = base + lane;
    int v = (i < nb) ? bsum[i] : 0;
    int x = v;
#pragma unroll
    for (int off = 1; off < 64; off <<= 1) {
      int t = __shfl_up(x, off);
      if (lane >= off) x += t;
    }
    if (i < nb) bsum[i] = carry + x - v;
    carry += __shfl(x, 63);
  }
  if (lane == 0) row_ptr[n] = carry;
}

__global__ __launch_bounds__(256) void scan3_kernel(
    int* __restrict__ cnt, const int* __restrict__ bsum,
    int* __restrict__ row_ptr, int n) {
  int i = blockIdx.x * 256 + threadIdx.x;
  if (i >= n) return;
  int v = cnt[i] + bsum[i >> 10];
  cnt[i] = v;
  row_ptr[i] = v;
}

__global__ __launch_bounds__(256) void scatter_kernel(
    const int* __restrict__ er, const int* __restrict__ ec,
    const float* __restrict__ ev, int* __restrict__ cursor,
    int2* __restrict__ cv, int E) {
  int i = blockIdx.x * 256 + threadIdx.x;
  if (i >= E) return;
  int r = er[i];
  int pos = atomicAdd(&cursor[r], 1);
  cv[pos] = make_int2(ec[i], __float_as_int(ev[i]));
}

// ---------------------------------------------------------------------------
// SPMM1 (CSR, F=256, bf16 in/out, fused ReLU): wave/row, 4 feats/lane, unroll 4
// ---------------------------------------------------------------------------
__global__ __launch_bounds__(256) void spmm_csr_256(
    const int* __restrict__ row_ptr, const int2* __restrict__ cv,
    const unsigned short* __restrict__ X, unsigned short* __restrict__ Y, int M) {
  int wave = (blockIdx.x * 256 + threadIdx.x) >> 6;
  int lane = threadIdx.x & 63;
  if (wave >= M) return;
  int start = row_ptr[wave], end = row_ptr[wave + 1];
  float a0 = 0.f, a1 = 0.f, a2 = 0.f, a3 = 0.f;
  const unsigned short* Xl = X + (lane << 2);
  int e = start;
  for (; e + 4 <= end; e += 4) {
    int2 p0 = cv[e], p1 = cv[e + 1], p2 = cv[e + 2], p3 = cv[e + 3];
    ushort4 x0 = *(const ushort4*)(Xl + (size_t)p0.x * N_HID);
    ushort4 x1 = *(const ushort4*)(Xl + (size_t)p1.x * N_HID);
    ushort4 x2 = *(const ushort4*)(Xl + (size_t)p2.x * N_HID);
    ushort4 x3 = *(const ushort4*)(Xl + (size_t)p3.x * N_HID);
    float v0 = __int_as_float(p0.y), v1 = __int_as_float(p1.y);
    float v2 = __int_as_float(p2.y), v3 = __int_as_float(p3.y);
    a0 = fmaf(v0, b2f(x0.x), a0); a1 = fmaf(v0, b2f(x0.y), a1);
    a2 = fmaf(v0, b2f(x0.z), a2); a3 = fmaf(v0, b2f(x0.w), a3);
    a0 = fmaf(v1, b2f(x1.x), a0); a1 = fmaf(v1, b2f(x1.y), a1);
    a2 = fmaf(v1, b2f(x1.z), a2); a3 = fmaf(v1, b2f(x1.w), a3);
    a0 = fmaf(v2, b2f(x2.x), a0); a1 = fmaf(v2, b2f(x2.y), a1);
    a2 = fmaf(v2, b2f(x2.z), a2); a3 = fmaf(v2, b2f(x2.w), a3);
    a0 = fmaf(v3, b2f(x3.x), a0); a1 = fmaf(v3, b2f(x3.y), a1);
    a2 = fmaf(v3, b2f(x3.z), a2); a3 = fmaf(v3, b2f(x3.w), a3);
  }
  for (; e < end; e++) {
    int2 p0 = cv[e];
    float v0 = __int_as_float(p0.y);
    ushort4 x0 = *(const ushort4*)(Xl + (size_t)p0.x * N_HID);
    a0 = fmaf(v0, b2f(x0.x), a0); a1 = fmaf(v0, b2f(x0.y), a1);
    a2 = fmaf(v0, b2f(x0.z), a2); a3 = fmaf(v0, b2f(x0.w), a3);
  }
  ushort4 o;
  o.x = f2bu(fmaxf(a0, 0.f)); o.y = f2bu(fmaxf(a1, 0.f));
  o.z = f2bu(fmaxf(a2, 0.f)); o.w = f2bu(fmaxf(a3, 0.f));
  *(ushort4*)(Y + (size_t)wave * N_HID + (lane << 2)) = o;
}

// ---------------------------------------------------------------------------
// GEMM2: O[M,40](bf16) = Hpost[M,256](bf16) @ W2[256,40] + b2; 2 rows/thread.
// ---------------------------------------------------------------------------
__global__ __launch_bounds__(256) void gemm2_kernel(
    const unsigned short* __restrict__ H, const float* __restrict__ W2,
    const float* __restrict__ b2, unsigned short* __restrict__ O, int M) {
  __shared__ float Ws[N_HID * N_CLASS];
  __shared__ float sb2[N_CLASS];
  int tid = threadIdx.x;
  for (int i = tid; i < N_HID * N_CLASS; i += 256) Ws[i] = W2[i];
  if (tid < N_CLASS) sb2[tid] = b2[tid];
  __syncthreads();
  int r0 = (blockIdx.x * 256 + tid) * 2;
  if (r0 >= M) return;
  int r1 = r0 + 1;
  bool has1 = r1 < M;
  float acc0[N_CLASS], acc1[N_CLASS];
#pragma unroll
  for (int n = 0; n < N_CLASS; n++) { acc0[n] = sb2[n]; acc1[n] = sb2[n]; }
  const unsigned short* h0 = H + (size_t)r0 * N_HID;
  const unsigned short* h1 = H + (size_t)(has1 ? r1 : r0) * N_HID;
  for (int k0 = 0; k0 < N_HID; k0 += 8) {
    u16x8 va = *(const u16x8*)(h0 + k0);
    u16x8 vb = *(const u16x8*)(h1 + k0);
#pragma unroll
    for (int j = 0; j < 8; j++) {
      float a0 = b2f(va[j]), a1 = b2f(vb[j]);
      const float* wrow = &Ws[(k0 + j) * N_CLASS];
#pragma unroll
      for (int n = 0; n < N_CLASS; n++) {
        float wv = wrow[n];
        acc0[n] = fmaf(a0, wv, acc0[n]);
        acc1[n] = fmaf(a1, wv, acc1[n]);
      }
    }
  }
  unsigned short* o0 = O + (size_t)r0 * N_CLASS;
#pragma unroll
  for (int n = 0; n < N_CLASS; n += 4) {
    ushort4 p;
    p.x = f2bu(acc0[n]); p.y = f2bu(acc0[n + 1]);
    p.z = f2bu(acc0[n + 2]); p.w = f2bu(acc0[n + 3]);
    *(ushort4*)(o0 + n) = p;
  }
  if (has1) {
    unsigned short* o1 = O + (size_t)r1 * N_CLASS;
#pragma unroll
    for (int n = 0; n < N_CLASS; n += 4) {
      ushort4 p;
      p.x = f2bu(acc1[n]); p.y = f2bu(acc1[n + 1]);
      p.z = f2bu(acc1[n + 2]); p.w = f2bu(acc1[n + 3]);
      *(ushort4*)(o1 + n) = p;
    }
  }
}

// ---------------------------------------------------------------------------
// SPMM2 (CSR, F=40, bf16 X) + fused log_softmax: wave/row, lanes 0..39, unroll 4
// ---------------------------------------------------------------------------
__global__ __launch_bounds__(256) void spmm_csr_40_lsm(
    const int* __restrict__ row_ptr, const int2* __restrict__ cv,
    const unsigned short* __restrict__ X, float* __restrict__ Out, int M) {
  int wave = (blockIdx.x * 256 + threadIdx.x) >> 6;
  int lane = threadIdx.x & 63;
  if (wave >= M) return;
  int start = row_ptr[wave], end = row_ptr[wave + 1];
  bool act = lane < N_CLASS;
  int ln = act ? lane : 0;
  const unsigned short* Xc = X + ln;
  float acc = 0.f;
  int e = start;
  for (; e + 4 <= end; e += 4) {
    int2 p0 = cv[e], p1 = cv[e + 1], p2 = cv[e + 2], p3 = cv[e + 3];
    unsigned short x0 = Xc[(size_t)p0.x * N_CLASS];
    unsigned short x1 = Xc[(size_t)p1.x * N_CLASS];
    unsigned short x2 = Xc[(size_t)p2.x * N_CLASS];
    unsigned short x3 = Xc[(size_t)p3.x * N_CLASS];
    acc = fmaf(__int_as_float(p0.y), b2f(x0), acc);
    acc = fmaf(__int_as_float(p1.y), b2f(x1), acc);
    acc = fmaf(__int_as_float(p2.y), b2f(x2), acc);
    acc = fmaf(__int_as_float(p3.y), b2f(x3), acc);
  }
  for (; e < end; e++) {
    int2 p0 = cv[e];
    acc = fmaf(__int_as_float(p0.y), b2f(Xc[(size_t)p0.x * N_CLASS]), acc);
  }
  float mv = act ? acc : -INFINITY;
#pragma unroll
  for (int off = 32; off; off >>= 1) mv = fmaxf(mv, __shfl_xor(mv, off));
  float ex = act ? expf(acc - mv) : 0.f;
  float s = ex;
#pragma unroll
  for (int off = 32; off; off >>= 1) s += __shfl_xor(s, off);
  float lse = mv + logf(s);
  if (act) Out[(size_t)wave * N_CLASS + lane] = acc - lse;
}

// ---------------------------------------------------------------------------
extern "C" void kernel_launch(void* const* d_in, const int* in_sizes, int n_in,
                              void* d_out, int out_size, void* d_ws, size_t ws_size,
                              hipStream_t stream) {
  const float* feat = (const float*)d_in[0];
  const int* er     = (const int*)d_in[1];
  const int* ec     = (const int*)d_in[2];
  const float* ev   = (const float*)d_in[3];
  const float* W1   = (const float*)d_in[4];
  const float* b1   = (const float*)d_in[5];
  const float* W2   = (const float*)d_in[6];
  const float* b2   = (const float*)d_in[7];
  float* out = (float*)d_out;
  const int M = N_NODES;
  const int E = in_sizes[1];

  char* ws = (char*)d_ws;
  unsigned short* h     = (unsigned short*)(ws);                 // 51.2 MB
  unsigned short* hpost = (unsigned short*)(ws + 51200000);      // 51.2 MB
  unsigned short* o     = (unsigned short*)(ws + 102400000);     // 8 MB bf16
  int* row_ptr          = (int*)(ws + 110400000);                // 400,004 B
  int* cursor           = (int*)(ws + 110800016);                // 400,000 B
  int* bsum             = (int*)(ws + 111200032);                // 512 B
  int2* cv              = (int2*)(ws + 111200576);               // 25.6 MB
  unsigned short* W1Tsw = (unsigned short*)(ws + 136800576);     // 256 KB

  const int NB1 = (M + 1023) / 1024;  // 98

  cast_w1<<<64, 256, 0, stream>>>(W1, W1Tsw);
  hipMemsetAsync(cursor, 0, (size_t)M * sizeof(int), stream);
  hist_kernel<<<(E + 255) / 256, 256, 0, stream>>>(er, cursor, E);
  scan1_kernel<<<NB1, 1024, 0, stream>>>(cursor, bsum, M);
  scan2_kernel<<<1, 64, 0, stream>>>(bsum, row_ptr, NB1, M);
  scan3_kernel<<<(M + 255) / 256, 256, 0, stream>>>(cursor, bsum, row_ptr, M);
  scatter_kernel<<<(E + 255) / 256, 256, 0, stream>>>(er, ec, ev, cursor, cv, E);
  gemm1_mfma<<<(M + 127) / 128, 512, 0, stream>>>(feat, W1Tsw, b1, h, M);
  spmm_csr_256<<<(M + 3) / 4, 256, 0, stream>>>(row_ptr, cv, h, hpost, M);
  gemm2_kernel<<<(M + 511) / 512, 256, 0, stream>>>(hpost, W2, b2, o, M);
  spmm_csr_40_lsm<<<(M + 3) / 4, 256, 0, stream>>>(row_ptr, cv, o, out, M);
}

// Round 6
// 789.946 us; speedup vs baseline: 16.5654x; 1.0073x over previous
//
#include <hip/hip_runtime.h>
#include <hip/hip_bf16.h>
#include <math.h>

#define N_NODES 100000
#define N_FEAT 500
#define N_HID 256
#define N_CLASS 40

typedef float f32x4 __attribute__((ext_vector_type(4)));
typedef int i32x4 __attribute__((ext_vector_type(4)));
typedef short short8 __attribute__((ext_vector_type(8)));
typedef unsigned short u16x8 __attribute__((ext_vector_type(8)));

__device__ __forceinline__ float b2f(unsigned short u) {
  union { unsigned int i; float f; } c; c.i = ((unsigned int)u) << 16; return c.f;
}
__device__ __forceinline__ unsigned short f2bu(float x) {
  __hip_bfloat16 b = __float2bfloat16(x);
  union { __hip_bfloat16 b; unsigned short u; } c; c.b = b; return c.u;
}
__device__ __forceinline__ void gload_lds16(const void* gptr, void* lptr) {
  __builtin_amdgcn_global_load_lds(
      (const __attribute__((address_space(1))) unsigned int*)gptr,
      (__attribute__((address_space(3))) unsigned int*)lptr, 16, 0, 0);
}

// ---------------------------------------------------------------------------
// cast W1[500][256] f32 -> W1T_sw[256][512] bf16 (transposed, padded, swizzled)
// ---------------------------------------------------------------------------
__global__ __launch_bounds__(256) void cast_w1(
    const float* __restrict__ W1, unsigned short* __restrict__ Bsw) {
  int t = blockIdx.x * 256 + threadIdx.x;
  int col = t >> 6, ch = t & 63;
  int g = ch >> 3, c = ch & 7;
  int c_src = c ^ (col & 7);
  int k = g * 64 + c_src * 8;
  u16x8 o;
#pragma unroll
  for (int j = 0; j < 8; j++) {
    int kk = k + j;
    o[j] = (kk < N_FEAT) ? f2bu(W1[(size_t)kk * N_HID + col]) : (unsigned short)0;
  }
  *(u16x8*)(Bsw + (size_t)col * 512 + g * 64 + c * 8) = o;
}

// ---------------------------------------------------------------------------
// GEMM1 (bf16 MFMA): H[M,256] = A[M,500] @ W1 + b1, bf16 out.
// ---------------------------------------------------------------------------
__global__ __launch_bounds__(512) void gemm1_mfma(
    const float* __restrict__ A, const unsigned short* __restrict__ Bsw,
    const float* __restrict__ b1, unsigned short* __restrict__ H, int M) {
  __shared__ __align__(16) char smem[49152];
  char* sA = smem;
  char* sB = smem + 16384;
  int tid = threadIdx.x;
  int lane = tid & 63, w = tid >> 6;
  int wr = w >> 2, wc = w & 3;
  int bm = blockIdx.x * 128;

  f32x4 acc[4][4];
#pragma unroll
  for (int m = 0; m < 4; m++)
#pragma unroll
    for (int n = 0; n < 4; n++) acc[m][n] = (f32x4)0.f;

  for (int s = 0; s < 8; s++) {
    int k0 = s * 64;
#pragma unroll
    for (int i = 0; i < 4; i++) {
      int f4 = i * 512 + tid;
      int row = f4 >> 4, cidx = f4 & 15;
      int grow = bm + row;
      int k = k0 + cidx * 4;
      float4 v = make_float4(0.f, 0.f, 0.f, 0.f);
      if (grow < M && k < N_FEAT) v = *(const float4*)(A + (size_t)grow * N_FEAT + k);
      ushort4 u;
      u.x = f2bu(v.x); u.y = f2bu(v.y); u.z = f2bu(v.z); u.w = f2bu(v.w);
      int chunk = cidx >> 1, sub = cidx & 1;
      int byte = row * 128 + (((chunk ^ (row & 7))) << 4) + (sub << 3);
      *(ushort4*)(sA + byte) = u;
    }
#pragma unroll
    for (int j = 0; j < 4; j++) {
      int base = j * 8192 + w * 1024;
      int L = base + lane * 16;
      int col = L >> 7, c = (L >> 4) & 7;
      const char* g = (const char*)Bsw + (size_t)col * 1024 + s * 128 + c * 16;
      gload_lds16(g, sB + base);
    }
    __syncthreads();
#pragma unroll
    for (int kk = 0; kk < 2; kk++) {
      int cw = kk * 4 + (lane >> 4);
      short8 af[4], bg[4];
#pragma unroll
      for (int m = 0; m < 4; m++) {
        int ar = wr * 64 + m * 16 + (lane & 15);
        af[m] = *(const short8*)(sA + ar * 128 + ((cw ^ (ar & 7)) << 4));
      }
#pragma unroll
      for (int n = 0; n < 4; n++) {
        int bc = wc * 64 + n * 16 + (lane & 15);
        bg[n] = *(const short8*)(sB + bc * 128 + ((cw ^ (bc & 7)) << 4));
      }
#pragma unroll
      for (int m = 0; m < 4; m++)
#pragma unroll
        for (int n = 0; n < 4; n++)
          acc[m][n] = __builtin_amdgcn_mfma_f32_16x16x32_bf16(af[m], bg[n], acc[m][n], 0, 0, 0);
    }
    __syncthreads();
  }

  float bias[4];
#pragma unroll
  for (int n = 0; n < 4; n++) bias[n] = b1[wc * 64 + n * 16 + (lane & 15)];
#pragma unroll
  for (int m = 0; m < 4; m++) {
#pragma unroll
    for (int r = 0; r < 4; r++) {
      int row = bm + wr * 64 + m * 16 + ((lane >> 4) << 2) + r;
      if (row < M) {
#pragma unroll
        for (int n = 0; n < 4; n++) {
          int col = wc * 64 + n * 16 + (lane & 15);
          H[(size_t)row * N_HID + col] = f2bu(acc[m][n][r] + bias[n]);
        }
      }
    }
  }
}

// ---------------------------------------------------------------------------
// CSR build: hist -> 3-phase scan -> XCD-sliced scatter
// ---------------------------------------------------------------------------
__global__ __launch_bounds__(256) void hist_kernel(
    const int* __restrict__ er, int* __restrict__ cnt, int E) {
  int nv = E >> 2;
  int t = blockIdx.x * 256 + threadIdx.x;
  int nthr = gridDim.x * 256;
  const i32x4* er4 = (const i32x4*)er;
  for (int i = t; i < nv; i += nthr) {
    i32x4 r = __builtin_nontemporal_load(&er4[i]);
    atomicAdd(&cnt[r.x], 1);
    atomicAdd(&cnt[r.y], 1);
    atomicAdd(&cnt[r.z], 1);
    atomicAdd(&cnt[r.w], 1);
  }
  int tail = nv << 2;
  if (blockIdx.x == 0 && threadIdx.x < E - tail)
    atomicAdd(&cnt[er[tail + threadIdx.x]], 1);
}

__global__ __launch_bounds__(1024) void scan1_kernel(
    int* __restrict__ cnt, int* __restrict__ bsum, int n) {
  __shared__ int wsum[16];
  int tid = threadIdx.x, lane = tid & 63, wid = tid >> 6;
  int i = blockIdx.x * 1024 + tid;
  int v = (i < n) ? cnt[i] : 0;
  int x = v;
#pragma unroll
  for (int off = 1; off < 64; off <<= 1) {
    int t = __shfl_up(x, off);
    if (lane >= off) x += t;
  }
  if (lane == 63) wsum[wid] = x;
  __syncthreads();
  if (tid < 16) {
    int ws = wsum[tid];
#pragma unroll
    for (int off = 1; off < 16; off <<= 1) {
      int t = __shfl_up(ws, off);
      if (tid >= off) ws += t;
    }
    wsum[tid] = ws;
  }
  __syncthreads();
  int excl = (wid ? wsum[wid - 1] : 0) + x - v;
  if (i < n) cnt[i] = excl;
  if (tid == 0) bsum[blockIdx.x] = wsum[15];
}

__global__ __launch_bounds__(64) void scan2_kernel(
    int* __restrict__ bsum, int* __restrict__ row_ptr, int nb, int n) {
  int lane = threadIdx.x;
  int carry = 0;
  for (int base = 0; base < nb; base += 64) {
    int i = base + lane;
    int v = (i < nb) ? bsum[i] : 0;
    int x = v;
#pragma unroll
    for (int off = 1; off < 64; off <<= 1) {
      int t = __shfl_up(x, off);
      if (lane >= off) x += t;
    }
    if (i < nb) bsum[i] = carry + x - v;
    carry += __shfl(x, 63);
  }
  if (lane == 0) row_ptr[n] = carry;
}

__global__ __launch_bounds__(256) void scan3_kernel(
    int* __restrict__ cnt, const int* __restrict__ bsum,
    int* __restrict__ row_ptr, int n) {
  int i = blockIdx.x * 256 + threadIdx.x;
  if (i >= n) return;
  int v = cnt[i] + bsum[i >> 10];
  cnt[i] = v;
  row_ptr[i] = v;
}

// XCD-sliced scatter: block b (on XCD b&7, empirical round-robin) processes
// only edges with slice(row) == b&7, where slice = (row>>9)&7. All stores +
// cursor atomics for a cv/cursor line then come from ONE XCD -> no cross-XCD
// line bouncing; lines pack in that XCD's L2 and write back once. Edge
// streams are read 8x but are L3-resident (38 MB).
__global__ __launch_bounds__(256) void scatter_kernel(
    const int* __restrict__ er, const int* __restrict__ ec,
    const float* __restrict__ ev, int* __restrict__ cursor,
    int2* __restrict__ cv, int E) {
  int s = blockIdx.x & 7;
  int g = blockIdx.x >> 3;
  int ngrp = gridDim.x >> 3;
  int t = g * 256 + threadIdx.x;
  int nthr = ngrp * 256;
  int nv = E >> 2;
  const i32x4* er4 = (const i32x4*)er;
  const i32x4* ec4 = (const i32x4*)ec;
  const f32x4* ev4 = (const f32x4*)ev;
  for (int i = t; i < nv; i += nthr) {
    i32x4 r = __builtin_nontemporal_load(&er4[i]);
    i32x4 c = __builtin_nontemporal_load(&ec4[i]);
    f32x4 v = __builtin_nontemporal_load(&ev4[i]);
    if (((r.x >> 9) & 7) == s) {
      int p = atomicAdd(&cursor[r.x], 1);
      cv[p] = make_int2(c.x, __float_as_int(v.x));
    }
    if (((r.y >> 9) & 7) == s) {
      int p = atomicAdd(&cursor[r.y], 1);
      cv[p] = make_int2(c.y, __float_as_int(v.y));
    }
    if (((r.z >> 9) & 7) == s) {
      int p = atomicAdd(&cursor[r.z], 1);
      cv[p] = make_int2(c.z, __float_as_int(v.z));
    }
    if (((r.w >> 9) & 7) == s) {
      int p = atomicAdd(&cursor[r.w], 1);
      cv[p] = make_int2(c.w, __float_as_int(v.w));
    }
  }
  // tail (E not multiple of 4): handled once by block 0
  int tail = nv << 2;
  if (blockIdx.x == 0 && threadIdx.x < E - tail) {
    int i = tail + threadIdx.x;
    int row = er[i];
    int p = atomicAdd(&cursor[row], 1);
    cv[p] = make_int2(ec[i], __float_as_int(ev[i]));
  }
}

// ---------------------------------------------------------------------------
// SPMM1 (CSR, F=256, bf16 in/out, fused ReLU): wave/row, 4 feats/lane, unroll 4
// ---------------------------------------------------------------------------
__global__ __launch_bounds__(256) void spmm_csr_256(
    const int* __restrict__ row_ptr, const int2* __restrict__ cv,
    const unsigned short* __restrict__ X, unsigned short* __restrict__ Y, int M) {
  int wave = (blockIdx.x * 256 + threadIdx.x) >> 6;
  int lane = threadIdx.x & 63;
  if (wave >= M) return;
  int start = row_ptr[wave], end = row_ptr[wave + 1];
  float a0 = 0.f, a1 = 0.f, a2 = 0.f, a3 = 0.f;
  const unsigned short* Xl = X + (lane << 2);
  int e = start;
  for (; e + 4 <= end; e += 4) {
    int2 p0 = cv[e], p1 = cv[e + 1], p2 = cv[e + 2], p3 = cv[e + 3];
    ushort4 x0 = *(const ushort4*)(Xl + (size_t)p0.x * N_HID);
    ushort4 x1 = *(const ushort4*)(Xl + (size_t)p1.x * N_HID);
    ushort4 x2 = *(const ushort4*)(Xl + (size_t)p2.x * N_HID);
    ushort4 x3 = *(const ushort4*)(Xl + (size_t)p3.x * N_HID);
    float v0 = __int_as_float(p0.y), v1 = __int_as_float(p1.y);
    float v2 = __int_as_float(p2.y), v3 = __int_as_float(p3.y);
    a0 = fmaf(v0, b2f(x0.x), a0); a1 = fmaf(v0, b2f(x0.y), a1);
    a2 = fmaf(v0, b2f(x0.z), a2); a3 = fmaf(v0, b2f(x0.w), a3);
    a0 = fmaf(v1, b2f(x1.x), a0); a1 = fmaf(v1, b2f(x1.y), a1);
    a2 = fmaf(v1, b2f(x1.z), a2); a3 = fmaf(v1, b2f(x1.w), a3);
    a0 = fmaf(v2, b2f(x2.x), a0); a1 = fmaf(v2, b2f(x2.y), a1);
    a2 = fmaf(v2, b2f(x2.z), a2); a3 = fmaf(v2, b2f(x2.w), a3);
    a0 = fmaf(v3, b2f(x3.x), a0); a1 = fmaf(v3, b2f(x3.y), a1);
    a2 = fmaf(v3, b2f(x3.z), a2); a3 = fmaf(v3, b2f(x3.w), a3);
  }
  for (; e < end; e++) {
    int2 p0 = cv[e];
    float v0 = __int_as_float(p0.y);
    ushort4 x0 = *(const ushort4*)(Xl + (size_t)p0.x * N_HID);
    a0 = fmaf(v0, b2f(x0.x), a0); a1 = fmaf(v0, b2f(x0.y), a1);
    a2 = fmaf(v0, b2f(x0.z), a2); a3 = fmaf(v0, b2f(x0.w), a3);
  }
  ushort4 o;
  o.x = f2bu(fmaxf(a0, 0.f)); o.y = f2bu(fmaxf(a1, 0.f));
  o.z = f2bu(fmaxf(a2, 0.f)); o.w = f2bu(fmaxf(a3, 0.f));
  *(ushort4*)(Y + (size_t)wave * N_HID + (lane << 2)) = o;
}

// ---------------------------------------------------------------------------
// GEMM2: O[M,40](bf16) = Hpost[M,256](bf16) @ W2[256,40] + b2; 2 rows/thread.
// ---------------------------------------------------------------------------
__global__ __launch_bounds__(256) void gemm2_kernel(
    const unsigned short* __restrict__ H, const float* __restrict__ W2,
    const float* __restrict__ b2, unsigned short* __restrict__ O, int M) {
  __shared__ float Ws[N_HID * N_CLASS];
  __shared__ float sb2[N_CLASS];
  int tid = threadIdx.x;
  for (int i = tid; i < N_HID * N_CLASS; i += 256) Ws[i] = W2[i];
  if (tid < N_CLASS) sb2[tid] = b2[tid];
  __syncthreads();
  int r0 = (blockIdx.x * 256 + tid) * 2;
  if (r0 >= M) return;
  int r1 = r0 + 1;
  bool has1 = r1 < M;
  float acc0[N_CLASS], acc1[N_CLASS];
#pragma unroll
  for (int n = 0; n < N_CLASS; n++) { acc0[n] = sb2[n]; acc1[n] = sb2[n]; }
  const unsigned short* h0 = H + (size_t)r0 * N_HID;
  const unsigned short* h1 = H + (size_t)(has1 ? r1 : r0) * N_HID;
  for (int k0 = 0; k0 < N_HID; k0 += 8) {
    u16x8 va = *(const u16x8*)(h0 + k0);
    u16x8 vb = *(const u16x8*)(h1 + k0);
#pragma unroll
    for (int j = 0; j < 8; j++) {
      float a0 = b2f(va[j]), a1 = b2f(vb[j]);
      const float* wrow = &Ws[(k0 + j) * N_CLASS];
#pragma unroll
      for (int n = 0; n < N_CLASS; n++) {
        float wv = wrow[n];
        acc0[n] = fmaf(a0, wv, acc0[n]);
        acc1[n] = fmaf(a1, wv, acc1[n]);
      }
    }
  }
  unsigned short* o0 = O + (size_t)r0 * N_CLASS;
#pragma unroll
  for (int n = 0; n < N_CLASS; n += 4) {
    ushort4 p;
    p.x = f2bu(acc0[n]); p.y = f2bu(acc0[n + 1]);
    p.z = f2bu(acc0[n + 2]); p.w = f2bu(acc0[n + 3]);
    *(ushort4*)(o0 + n) = p;
  }
  if (has1) {
    unsigned short* o1 = O + (size_t)r1 * N_CLASS;
#pragma unroll
    for (int n = 0; n < N_CLASS; n += 4) {
      ushort4 p;
      p.x = f2bu(acc1[n]); p.y = f2bu(acc1[n + 1]);
      p.z = f2bu(acc1[n + 2]); p.w = f2bu(acc1[n + 3]);
      *(ushort4*)(o1 + n) = p;
    }
  }
}

// ---------------------------------------------------------------------------
// SPMM2 (CSR, F=40, bf16 X) + fused log_softmax: wave/row, lanes 0..39, unroll 4
// ---------------------------------------------------------------------------
__global__ __launch_bounds__(256) void spmm_csr_40_lsm(
    const int* __restrict__ row_ptr, const int2* __restrict__ cv,
    const unsigned short* __restrict__ X, float* __restrict__ Out, int M) {
  int wave = (blockIdx.x * 256 + threadIdx.x) >> 6;
  int lane = threadIdx.x & 63;
  if (wave >= M) return;
  int start = row_ptr[wave], end = row_ptr[wave + 1];
  bool act = lane < N_CLASS;
  int ln = act ? lane : 0;
  const unsigned short* Xc = X + ln;
  float acc = 0.f;
  int e = start;
  for (; e + 4 <= end; e += 4) {
    int2 p0 = cv[e], p1 = cv[e + 1], p2 = cv[e + 2], p3 = cv[e + 3];
    unsigned short x0 = Xc[(size_t)p0.x * N_CLASS];
    unsigned short x1 = Xc[(size_t)p1.x * N_CLASS];
    unsigned short x2 = Xc[(size_t)p2.x * N_CLASS];
    unsigned short x3 = Xc[(size_t)p3.x * N_CLASS];
    acc = fmaf(__int_as_float(p0.y), b2f(x0), acc);
    acc = fmaf(__int_as_float(p1.y), b2f(x1), acc);
    acc = fmaf(__int_as_float(p2.y), b2f(x2), acc);
    acc = fmaf(__int_as_float(p3.y), b2f(x3), acc);
  }
  for (; e < end; e++) {
    int2 p0 = cv[e];
    acc = fmaf(__int_as_float(p0.y), b2f(Xc[(size_t)p0.x * N_CLASS]), acc);
  }
  float mv = act ? acc : -INFINITY;
#pragma unroll
  for (int off = 32; off; off >>= 1) mv = fmaxf(mv, __shfl_xor(mv, off));
  float ex = act ? expf(acc - mv) : 0.f;
  float s = ex;
#pragma unroll
  for (int off = 32; off; off >>= 1) s += __shfl_xor(s, off);
  float lse = mv + logf(s);
  if (act) Out[(size_t)wave * N_CLASS + lane] = acc - lse;
}

// ---------------------------------------------------------------------------
extern "C" void kernel_launch(void* const* d_in, const int* in_sizes, int n_in,
                              void* d_out, int out_size, void* d_ws, size_t ws_size,
                              hipStream_t stream) {
  const float* feat = (const float*)d_in[0];
  const int* er     = (const int*)d_in[1];
  const int* ec     = (const int*)d_in[2];
  const float* ev   = (const float*)d_in[3];
  const float* W1   = (const float*)d_in[4];
  const float* b1   = (const float*)d_in[5];
  const float* W2   = (const float*)d_in[6];
  const float* b2   = (const float*)d_in[7];
  float* out = (float*)d_out;
  const int M = N_NODES;
  const int E = in_sizes[1];

  char* ws = (char*)d_ws;
  unsigned short* h     = (unsigned short*)(ws);                 // 51.2 MB
  unsigned short* hpost = (unsigned short*)(ws + 51200000);      // 51.2 MB
  unsigned short* o     = (unsigned short*)(ws + 102400000);     // 8 MB bf16
  int* row_ptr          = (int*)(ws + 110400000);                // 400,004 B
  int* cursor           = (int*)(ws + 110800016);                // 400,000 B
  int* bsum             = (int*)(ws + 111200032);                // 512 B
  int2* cv              = (int2*)(ws + 111200576);               // 25.6 MB
  unsigned short* W1Tsw = (unsigned short*)(ws + 136800576);     // 256 KB

  const int NB1 = (M + 1023) / 1024;  // 98

  cast_w1<<<64, 256, 0, stream>>>(W1, W1Tsw);
  (void)hipMemsetAsync(cursor, 0, (size_t)M * sizeof(int), stream);
  hist_kernel<<<1024, 256, 0, stream>>>(er, cursor, E);
  scan1_kernel<<<NB1, 1024, 0, stream>>>(cursor, bsum, M);
  scan2_kernel<<<1, 64, 0, stream>>>(bsum, row_ptr, NB1, M);
  scan3_kernel<<<(M + 255) / 256, 256, 0, stream>>>(cursor, bsum, row_ptr, M);
  scatter_kernel<<<2048, 256, 0, stream>>>(er, ec, ev, cursor, cv, E);
  gemm1_mfma<<<(M + 127) / 128, 512, 0, stream>>>(feat, W1Tsw, b1, h, M);
  spmm_csr_256<<<(M + 3) / 4, 256, 0, stream>>>(row_ptr, cv, h, hpost, M);
  gemm2_kernel<<<(M + 511) / 512, 256, 0, stream>>>(hpost, W2, b2, o, M);
  spmm_csr_40_lsm<<<(M + 3) / 4, 256, 0, stream>>>(row_ptr, cv, o, out, M);
}